// Round 3
// baseline (668.559 us; speedup 1.0000x reference)
//
#include <hip/hip_runtime.h>
#include <hip/hip_bf16.h>
#include <math.h>

#define D 64

typedef __attribute__((ext_vector_type(8))) short bf16x8;
typedef __attribute__((ext_vector_type(4))) float f32x4;

__device__ __forceinline__ float bcast(float v, int l) {
    return __uint_as_float(__builtin_amdgcn_readlane(__float_as_uint(v), l));
}
__device__ __forceinline__ float gelu_erf(float x) {
    return 0.5f * x * (1.0f + erff(x * 0.70710678118654752f));
}
// branchless tanh-gelu: max err ~3e-3 vs erf-gelu
__device__ __forceinline__ float gelu_tanh(float x) {
    float u = x * fmaf(x * x, 0.035677408136f, 0.7978845608028654f);
    float e = __expf(2.0f * u);
    float th = 1.0f - 2.0f / (e + 1.0f);
    return 0.5f * x * (1.0f + th);
}
__device__ __forceinline__ unsigned short f2bf(float v) {
    __hip_bfloat16 h = __float2bfloat16(v);
    return *(unsigned short*)&h;
}

// ---- pack Wt/Wq (B[k][n]=W[n*ld+k]) and Wks/Wkd (B[k][n]=W[k*64+n]) into
// bf16 B-fragments for mfma_f32_16x16x32_bf16. frag f = ntile*2+kk.
__global__ void prep_weights(const float* __restrict__ Wt, const float* __restrict__ Wq,
                             const float* __restrict__ Wks, const float* __restrict__ Wkd,
                             unsigned short* __restrict__ WtB, unsigned short* __restrict__ WqB,
                             unsigned short* __restrict__ WksB, unsigned short* __restrict__ WkdB)
{
    int lane = threadIdx.x & 63;
    int w = threadIdx.x >> 6;
    int c = lane & 15, quad = lane >> 4;
    for (int f = 0; f < 8; ++f) {
        int ntile = f >> 1, kk = f & 1;
        for (int j = 0; j < 8; ++j) {
            int n = ntile * 16 + c, k = kk * 32 + quad * 8 + j;
            float v; unsigned short* dstp;
            if (w == 0)      { v = Wt[n * 65 + k];  dstp = WtB; }
            else if (w == 1) { v = Wq[n * 64 + k];  dstp = WqB; }
            else if (w == 2) { v = Wks[k * 64 + n]; dstp = WksB; }
            else             { v = Wkd[k * 64 + n]; dstp = WkdB; }
            dstp[(f * 64 + lane) * 8 + j] = f2bf(v);
        }
    }
}

// ---- LayerNorm -> bf16 xn
__global__ __launch_bounds__(256) void ln_kernel(
    const float* __restrict__ x, const float* __restrict__ gamma, const float* __restrict__ beta,
    unsigned short* __restrict__ xnb, int N)
{
    const int lane = threadIdx.x & 63;
    const int wave = blockIdx.x * 4 + (threadIdx.x >> 6);
    const int nwaves = gridDim.x * 4;
    const float g = gamma[lane], b = beta[lane];
    for (int n = wave; n < N; n += nwaves) {
        float xv = x[(long)n * D + lane];
        float s = xv;
        #pragma unroll
        for (int o = 32; o; o >>= 1) s += __shfl_xor(s, o);
        float mu = s * (1.0f / 64.0f);
        float d0 = xv - mu;
        float s2 = d0 * d0;
        #pragma unroll
        for (int o = 32; o; o >>= 1) s2 += __shfl_xor(s2, o);
        float xh = d0 * rsqrtf(s2 * (1.0f / 64.0f) + 1e-5f) * g + b;
        xnb[(long)n * D + lane] = f2bf(xh);
    }
}

// ---- CSR build
__global__ void hist_kernel(const int* __restrict__ ei, int* __restrict__ cnt, int E) {
    int stride = gridDim.x * blockDim.x;
    for (int e = blockIdx.x * blockDim.x + threadIdx.x; e < E; e += stride)
        atomicAdd(&cnt[ei[E + e]], 1);
}

__global__ __launch_bounds__(1024) void scan_kernel(const int* __restrict__ cnt,
    int* __restrict__ row_start, int* __restrict__ cursor, int N)
{
    __shared__ int part[1024];
    int tid = threadIdx.x;
    int chunk = (N + 1023) >> 10;
    int lo = tid * chunk, hi = min(lo + chunk, N);
    int s = 0;
    for (int i = lo; i < hi; ++i) s += cnt[i];
    part[tid] = s;
    __syncthreads();
    for (int o = 1; o < 1024; o <<= 1) {
        int v = (tid >= o) ? part[tid - o] : 0;
        __syncthreads();
        part[tid] += v;
        __syncthreads();
    }
    int base = (tid == 0) ? 0 : part[tid - 1];
    for (int i = lo; i < hi; ++i) {
        row_start[i] = base; cursor[i] = base; base += cnt[i];
    }
}

__global__ void scatter_kernel(const int* __restrict__ ei, const float* __restrict__ et,
    const float* __restrict__ esame, int* __restrict__ cursor,
    int* __restrict__ esrc, float* __restrict__ ets, int E)
{
    int stride = gridDim.x * blockDim.x;
    for (int e = blockIdx.x * blockDim.x + threadIdx.x; e < E; e += stride) {
        int dst = ei[E + e];
        int pos = atomicAdd(&cursor[dst], 1);
        int sv = ei[e];
        if (esame[e] > 0.5f) sv = sv | 0x80000000;
        esrc[pos] = sv;
        ets[pos] = et[e];
    }
}

// ---- q-chain, all-MFMA: q = xn@Wq^T + bq ; qks = q@Wks ; qkd = q@Wkd ;
//      bqs = q.bks ; bqd = q.bkd      (16 nodes per wave)
__global__ __launch_bounds__(256) void qgemm(
    const unsigned short* __restrict__ xnb,
    const unsigned short* __restrict__ WqB, const unsigned short* __restrict__ WksB,
    const unsigned short* __restrict__ WkdB,
    const float* __restrict__ bq, const float* __restrict__ bks, const float* __restrict__ bkd,
    float* __restrict__ qks, float* __restrict__ qkd,
    float* __restrict__ bqs, float* __restrict__ bqd, int N)
{
    __shared__ unsigned short qtile[4][16 * 64];
    const int lane = threadIdx.x & 63;
    const int c = lane & 15, quad = lane >> 4;
    const int w = threadIdx.x >> 6;
    const int wave = blockIdx.x * 4 + w;
    const int n0r = wave * 16;
    const bool active = n0r < N;
    const int n0 = active ? n0r : 0;

    float bqc[4], bksc[4], bkdc[4];
    #pragma unroll
    for (int t = 0; t < 4; ++t) {
        bqc[t] = bq[t * 16 + c]; bksc[t] = bks[t * 16 + c]; bkdc[t] = bkd[t * 16 + c];
    }

    // GEMM1: q
    const unsigned short* arow = xnb + (long)(n0 + c) * D + quad * 8;
    bf16x8 a0 = *(const bf16x8*)(arow);
    bf16x8 a1 = *(const bf16x8*)(arow + 32);
    f32x4 accq[4];
    #pragma unroll
    for (int t = 0; t < 4; ++t) {
        bf16x8 b0 = *(const bf16x8*)(WqB + ((t * 2 + 0) * 64 + lane) * 8);
        bf16x8 b1 = *(const bf16x8*)(WqB + ((t * 2 + 1) * 64 + lane) * 8);
        f32x4 z = {0.f, 0.f, 0.f, 0.f};
        z = __builtin_amdgcn_mfma_f32_16x16x32_bf16(a0, b0, z, 0, 0, 0);
        z = __builtin_amdgcn_mfma_f32_16x16x32_bf16(a1, b1, z, 0, 0, 0);
        accq[t] = z;
    }
    // epilogue 1: +bq, dots with bks/bkd, store bf16 tile
    #pragma unroll
    for (int r = 0; r < 4; ++r) {
        float qv[4], ss = 0.f, sd = 0.f;
        #pragma unroll
        for (int t = 0; t < 4; ++t) {
            qv[t] = accq[t][r] + bqc[t];
            ss = fmaf(qv[t], bksc[t], ss);
            sd = fmaf(qv[t], bkdc[t], sd);
        }
        #pragma unroll
        for (int o = 1; o < 16; o <<= 1) { ss += __shfl_xor(ss, o); sd += __shfl_xor(sd, o); }
        if (active && c == 0) {
            bqs[n0 + quad * 4 + r] = ss;
            bqd[n0 + quad * 4 + r] = sd;
        }
        #pragma unroll
        for (int t = 0; t < 4; ++t)
            qtile[w][(quad * 4 + r) * 64 + t * 16 + c] = f2bf(qv[t]);
    }
    __syncthreads();

    // GEMM2: qks / qkd
    const unsigned short* qrow = &qtile[w][c * 64 + quad * 8];
    bf16x8 q0 = *(const bf16x8*)(qrow);
    bf16x8 q1 = *(const bf16x8*)(qrow + 32);
    #pragma unroll
    for (int t = 0; t < 4; ++t) {
        bf16x8 bs0 = *(const bf16x8*)(WksB + ((t * 2 + 0) * 64 + lane) * 8);
        bf16x8 bs1 = *(const bf16x8*)(WksB + ((t * 2 + 1) * 64 + lane) * 8);
        bf16x8 bd0 = *(const bf16x8*)(WkdB + ((t * 2 + 0) * 64 + lane) * 8);
        bf16x8 bd1 = *(const bf16x8*)(WkdB + ((t * 2 + 1) * 64 + lane) * 8);
        f32x4 zs = {0.f, 0.f, 0.f, 0.f}, zd = {0.f, 0.f, 0.f, 0.f};
        zs = __builtin_amdgcn_mfma_f32_16x16x32_bf16(q0, bs0, zs, 0, 0, 0);
        zs = __builtin_amdgcn_mfma_f32_16x16x32_bf16(q1, bs1, zs, 0, 0, 0);
        zd = __builtin_amdgcn_mfma_f32_16x16x32_bf16(q0, bd0, zd, 0, 0, 0);
        zd = __builtin_amdgcn_mfma_f32_16x16x32_bf16(q1, bd1, zd, 0, 0, 0);
        if (active) {
            #pragma unroll
            for (int r = 0; r < 4; ++r) {
                long row = (long)(n0 + quad * 4 + r) * D + t * 16 + c;
                qks[row] = zs[r];
                qkd[row] = zd[r];
            }
        }
    }
}

// ---- fused edge pass + aggregation + node_post. One wave per dst (grid-stride).
__global__ __launch_bounds__(256) void edge_fused(
    const int* __restrict__ row_start, const int* __restrict__ cnt,
    const int* __restrict__ esrc, const float* __restrict__ ets,
    const unsigned short* __restrict__ xnb, const unsigned short* __restrict__ WtB,
    const float* __restrict__ Wt, const float* __restrict__ bt,
    const float* __restrict__ qks, const float* __restrict__ qkd,
    const float* __restrict__ bqs, const float* __restrict__ bqd,
    const float* __restrict__ Wvs, const float* __restrict__ bvs,
    const float* __restrict__ Wvd, const float* __restrict__ bvd,
    const float* __restrict__ x, float* __restrict__ out, int N)
{
    __shared__ float WvsL[64 * 65];
    __shared__ float WvdL[64 * 65];
    for (int idx = threadIdx.x; idx < 4096; idx += 256) {
        int i = idx >> 6, j = idx & 63;
        WvsL[i * 65 + j] = Wvs[idx];
        WvdL[i * 65 + j] = Wvd[idx];
    }
    __syncthreads();

    const int lane = threadIdx.x & 63;
    const int c = lane & 15, quad = lane >> 4;
    const int wave0 = blockIdx.x * 4 + (threadIdx.x >> 6);
    const int nwaves = gridDim.x * 4;

    bf16x8 bfrag[8];
    #pragma unroll
    for (int f = 0; f < 8; ++f)
        bfrag[f] = *(const bf16x8*)(WtB + (f * 64 + lane) * 8);

    float btc[4], w64c[4], dva[4];
    #pragma unroll
    for (int t = 0; t < 4; ++t) {
        int dim = t * 16 + c;
        btc[t] = bt[dim];
        w64c[t] = Wt[dim * 65 + 64];
        dva[t] = 200.0f * expf(-9.210340371976184f * (float)(2 * (dim >> 1)) * (1.0f / 64.0f));
    }
    const float phoff = (c & 1) ? 1.5707963267948966f : 0.0f;  // cos = sin(x+pi/2)
    const float bvsv = bvs[lane], bvdv = bvd[lane];

    for (int n = wave0; n < N; n += nwaves) {
        const int start = row_start[n];
        const int deg = cnt[n];
        float qk_s[4], qk_d[4];
        #pragma unroll
        for (int t = 0; t < 4; ++t) {
            qk_s[t] = qks[(long)n * D + t * 16 + c];
            qk_d[t] = qkd[(long)n * D + t * 16 + c];
        }
        const float bq_s = bqs[n], bq_d = bqd[n];

        float acc_s[4][4], acc_d[4][4];
        #pragma unroll
        for (int t = 0; t < 4; ++t)
            #pragma unroll
            for (int r = 0; r < 4; ++r) { acc_s[t][r] = 0.f; acc_d[t][r] = 0.f; }
        float den_s = 0.f, den_d = 0.f;

        for (int off = 0; off < deg; off += 16) {
            int ml = off + c;
            int idx = start + (ml < deg ? ml : deg - 1);
            int sv = esrc[idx];
            float tv = ets[idx];
            int src = sv & 0x7fffffff;

            const unsigned short* arow = xnb + (long)src * D + quad * 8;
            bf16x8 a0 = *(const bf16x8*)(arow);
            bf16x8 a1 = *(const bf16x8*)(arow + 32);

            f32x4 accC[4];
            #pragma unroll
            for (int t = 0; t < 4; ++t) {
                f32x4 z = {0.f, 0.f, 0.f, 0.f};
                z = __builtin_amdgcn_mfma_f32_16x16x32_bf16(a0, bfrag[t * 2 + 0], z, 0, 0, 0);
                z = __builtin_amdgcn_mfma_f32_16x16x32_bf16(a1, bfrag[t * 2 + 1], z, 0, 0, 0);
                accC[t] = z;
            }

            #pragma unroll
            for (int r = 0; r < 4; ++r) {
                int m = quad * 4 + r;
                int svm = __shfl(sv, m);
                float tm = __shfl(tv, m);
                bool same = svm < 0;
                bool valid = (off + m) < deg;

                float xtv[4], p = 0.f;
                #pragma unroll
                for (int t = 0; t < 4; ++t) {
                    float v = gelu_tanh(accC[t][r] + fmaf(tm, w64c[t], btc[t]));
                    v += __sinf(fmaf(tm, dva[t], phoff));
                    xtv[t] = v;
                    p = fmaf(v, same ? qk_s[t] : qk_d[t], p);
                }
                #pragma unroll
                for (int o = 1; o < 16; o <<= 1) p += __shfl_xor(p, o);
                float ex = valid ? __expf((p + (same ? bq_s : bq_d)) * 0.125f) : 0.0f;
                if (same) {
                    den_s += ex;
                    #pragma unroll
                    for (int t = 0; t < 4; ++t) acc_s[t][r] = fmaf(ex, xtv[t], acc_s[t][r]);
                } else {
                    den_d += ex;
                    #pragma unroll
                    for (int t = 0; t < 4; ++t) acc_d[t][r] = fmaf(ex, xtv[t], acc_d[t][r]);
                }
            }
        }

        // reduce over the 16 C-rows (4 in-lane r + 4 quads)
        float as[4], ad[4];
        #pragma unroll
        for (int t = 0; t < 4; ++t) {
            float s = (acc_s[t][0] + acc_s[t][1]) + (acc_s[t][2] + acc_s[t][3]);
            s += __shfl_xor(s, 16); s += __shfl_xor(s, 32);
            as[t] = s;
            float d2 = (acc_d[t][0] + acc_d[t][1]) + (acc_d[t][2] + acc_d[t][3]);
            d2 += __shfl_xor(d2, 16); d2 += __shfl_xor(d2, 32);
            ad[t] = d2;
        }
        den_s += __shfl_xor(den_s, 16); den_s += __shfl_xor(den_s, 32);
        den_d += __shfl_xor(den_d, 16); den_d += __shfl_xor(den_d, 32);

        float inv = 1.0f / (den_s + den_d + 1e-16f);
        #pragma unroll
        for (int t = 0; t < 4; ++t) { as[t] *= inv; ad[t] *= inv; }

        float o = (den_s * inv) * bvsv + (den_d * inv) * bvdv;
        #pragma unroll
        for (int j = 0; j < 64; ++j) {
            o = fmaf(WvsL[lane * 65 + j], bcast(as[j >> 4], j & 15), o);
            o = fmaf(WvdL[lane * 65 + j], bcast(ad[j >> 4], j & 15), o);
        }
        out[(long)n * D + lane] = x[(long)n * D + lane] + gelu_erf(o);
    }
}

extern "C" void kernel_launch(void* const* d_in, const int* in_sizes, int n_in,
                              void* d_out, int out_size, void* d_ws, size_t ws_size,
                              hipStream_t stream) {
    const float* x        = (const float*)d_in[0];
    const int*   ei       = (const int*)d_in[1];
    const float* et       = (const float*)d_in[2];
    const float* esame    = (const float*)d_in[4];
    const float* ln_gamma = (const float*)d_in[5];
    const float* ln_beta  = (const float*)d_in[6];
    const float* Wt  = (const float*)d_in[7];
    const float* bt  = (const float*)d_in[8];
    const float* Wq  = (const float*)d_in[9];
    const float* bq  = (const float*)d_in[10];
    const float* Wks = (const float*)d_in[11];
    const float* bks = (const float*)d_in[12];
    const float* Wkd = (const float*)d_in[13];
    const float* bkd = (const float*)d_in[14];
    const float* Wvs = (const float*)d_in[15];
    const float* bvs = (const float*)d_in[16];
    const float* Wvd = (const float*)d_in[17];
    const float* bvd = (const float*)d_in[18];
    float* out = (float*)d_out;

    const int N = in_sizes[0] / D;   // 50000
    const int E = in_sizes[2];       // 800000

    float* w = (float*)d_ws;
    float* qks = w;       w += (long)N * D;
    float* qkd = w;       w += (long)N * D;
    float* bqs = w;       w += N;
    float* bqd = w;       w += N;
    int* cnt = (int*)w;       w += N;
    int* cursor = (int*)w;    w += N;
    int* row_start = (int*)w; w += N;
    int* esrc = (int*)w;      w += E;
    float* ets = w;           w += E;
    unsigned short* xnb = (unsigned short*)w; w += (long)N * D / 2;
    unsigned short* WtB  = (unsigned short*)w; w += 2048;
    unsigned short* WqB  = (unsigned short*)w; w += 2048;
    unsigned short* WksB = (unsigned short*)w; w += 2048;
    unsigned short* WkdB = (unsigned short*)w; w += 2048;

    hipMemsetAsync(cnt, 0, (size_t)N * sizeof(int), stream);

    prep_weights<<<1, 256, 0, stream>>>(Wt, Wq, Wks, Wkd, WtB, WqB, WksB, WkdB);
    ln_kernel<<<512, 256, 0, stream>>>(x, ln_gamma, ln_beta, xnb, N);
    hist_kernel<<<1024, 256, 0, stream>>>(ei, cnt, E);
    scan_kernel<<<1, 1024, 0, stream>>>(cnt, row_start, cursor, N);
    scatter_kernel<<<1024, 256, 0, stream>>>(ei, et, esame, cursor, esrc, ets, E);
    qgemm<<<(N / 16 + 3) / 4, 256, 0, stream>>>(xnb, WqB, WksB, WkdB, bq, bks, bkd,
                                                qks, qkd, bqs, bqd, N);
    edge_fused<<<3125, 256, 0, stream>>>(row_start, cnt, esrc, ets, xnb, WtB, Wt, bt,
                                         qks, qkd, bqs, bqd, Wvs, bvs, Wvd, bvd,
                                         x, out, N);
}

// Round 4
// 376.269 us; speedup vs baseline: 1.7768x; 1.7768x over previous
//
#include <hip/hip_runtime.h>
#include <hip/hip_bf16.h>
#include <math.h>

#define D 64

typedef __attribute__((ext_vector_type(8))) short bf16x8;
typedef __attribute__((ext_vector_type(8))) _Float16 f16x8;
typedef __attribute__((ext_vector_type(4))) float f32x4;
typedef unsigned short u16;

__device__ __forceinline__ float gelu_erf(float x) {
    return 0.5f * x * (1.0f + erff(x * 0.70710678118654752f));
}
// branchless tanh-gelu: max err ~3e-3 vs erf-gelu
__device__ __forceinline__ float gelu_tanh(float x) {
    float u = x * fmaf(x * x, 0.035677408136f, 0.7978845608028654f);
    float e = __expf(2.0f * u);
    float th = 1.0f - 2.0f / (e + 1.0f);
    return 0.5f * x * (1.0f + th);
}
__device__ __forceinline__ u16 f2bf(float v) {
    __hip_bfloat16 h = __float2bfloat16(v);
    return *(u16*)&h;
}
__device__ __forceinline__ float bf2f(u16 v) {
    return __uint_as_float(((unsigned int)v) << 16);
}
__device__ __forceinline__ u16 f2h(float v) {
    _Float16 h = (_Float16)v;
    return __builtin_bit_cast(u16, h);
}
// packed f16 atomic add (device scope). 2 dims per op -> half the atomic traffic.
__device__ __forceinline__ void atomic_pk_add_f16(u16* addr, float lo, float hi) {
    unsigned int p = (unsigned int)f2h(lo) | ((unsigned int)f2h(hi) << 16);
    asm volatile("global_atomic_pk_add_f16 %0, %1, off sc1" :: "v"(addr), "v"(p) : "memory");
}

// ---- pack weights into MFMA B-fragments (frag f = ntile*2+kk; lane holds
// B[k=kk*32+quad*8+j][n=ntile*16+c]).  Wt/Wq/Wvs/Wvd: B[k][n]=W[n*ld+k];
// Wks/Wkd: B[k][n]=W[k*64+n].  Wt..Wkd -> bf16, Wvs/Wvd -> f16.
__global__ void prep_weights(const float* __restrict__ Wt, const float* __restrict__ Wq,
                             const float* __restrict__ Wks, const float* __restrict__ Wkd,
                             const float* __restrict__ Wvs, const float* __restrict__ Wvd,
                             u16* __restrict__ WtB, u16* __restrict__ WqB,
                             u16* __restrict__ WksB, u16* __restrict__ WkdB,
                             u16* __restrict__ WvsB, u16* __restrict__ WvdB)
{
    int lane = threadIdx.x & 63;
    int w = threadIdx.x >> 6;   // 0..5
    int c = lane & 15, quad = lane >> 4;
    for (int f = 0; f < 8; ++f) {
        int nt = f >> 1, kk = f & 1;
        for (int j = 0; j < 8; ++j) {
            int n = nt * 16 + c, k = kk * 32 + quad * 8 + j;
            float v; u16* dp; bool half16 = false;
            switch (w) {
                case 0: v = Wt[n * 65 + k];  dp = WtB;  break;
                case 1: v = Wq[n * 64 + k];  dp = WqB;  break;
                case 2: v = Wks[k * 64 + n]; dp = WksB; break;
                case 3: v = Wkd[k * 64 + n]; dp = WkdB; break;
                case 4: v = Wvs[n * 64 + k]; dp = WvsB; half16 = true; break;
                default: v = Wvd[n * 64 + k]; dp = WvdB; half16 = true; break;
            }
            dp[(f * 64 + lane) * 8 + j] = half16 ? f2h(v) : f2bf(v);
        }
    }
}

// ---- LayerNorm -> bf16 xn
__global__ __launch_bounds__(256) void ln_kernel(
    const float* __restrict__ x, const float* __restrict__ gamma, const float* __restrict__ beta,
    u16* __restrict__ xnb, int N)
{
    const int lane = threadIdx.x & 63;
    const int wave = blockIdx.x * 4 + (threadIdx.x >> 6);
    const int nwaves = gridDim.x * 4;
    const float g = gamma[lane], b = beta[lane];
    for (int n = wave; n < N; n += nwaves) {
        float xv = x[(long)n * D + lane];
        float s = xv;
        #pragma unroll
        for (int o = 32; o; o >>= 1) s += __shfl_xor(s, o);
        float mu = s * (1.0f / 64.0f);
        float d0 = xv - mu;
        float s2 = d0 * d0;
        #pragma unroll
        for (int o = 32; o; o >>= 1) s2 += __shfl_xor(s2, o);
        float xh = d0 * rsqrtf(s2 * (1.0f / 64.0f) + 1e-5f) * g + b;
        xnb[(long)n * D + lane] = f2bf(xh);
    }
}

// ---- q-chain, all-MFMA: q = xn@Wq^T + bq ; qks = q@Wks ; qkd = q@Wkd (bf16 out);
//      bqs = q.bks ; bqd = q.bkd      (16 nodes per wave)
__global__ __launch_bounds__(256) void qgemm(
    const u16* __restrict__ xnb,
    const u16* __restrict__ WqB, const u16* __restrict__ WksB, const u16* __restrict__ WkdB,
    const float* __restrict__ bq, const float* __restrict__ bks, const float* __restrict__ bkd,
    u16* __restrict__ qksb, u16* __restrict__ qkdb,
    float* __restrict__ bqs, float* __restrict__ bqd, int N)
{
    __shared__ u16 qtile[4][16 * 64];
    const int lane = threadIdx.x & 63;
    const int c = lane & 15, quad = lane >> 4;
    const int w = threadIdx.x >> 6;
    const int wave = blockIdx.x * 4 + w;
    const int n0r = wave * 16;
    const bool active = n0r < N;
    const int n0 = active ? n0r : 0;
    const int rowA = (n0 + c < N) ? n0 + c : N - 1;

    float bqc[4], bksc[4], bkdc[4];
    #pragma unroll
    for (int t = 0; t < 4; ++t) {
        bqc[t] = bq[t * 16 + c]; bksc[t] = bks[t * 16 + c]; bkdc[t] = bkd[t * 16 + c];
    }

    const u16* arow = xnb + (long)rowA * D + quad * 8;
    bf16x8 a0 = *(const bf16x8*)(arow);
    bf16x8 a1 = *(const bf16x8*)(arow + 32);
    f32x4 accq[4];
    #pragma unroll
    for (int t = 0; t < 4; ++t) {
        bf16x8 b0 = *(const bf16x8*)(WqB + ((t * 2 + 0) * 64 + lane) * 8);
        bf16x8 b1 = *(const bf16x8*)(WqB + ((t * 2 + 1) * 64 + lane) * 8);
        f32x4 z = {0.f, 0.f, 0.f, 0.f};
        z = __builtin_amdgcn_mfma_f32_16x16x32_bf16(a0, b0, z, 0, 0, 0);
        z = __builtin_amdgcn_mfma_f32_16x16x32_bf16(a1, b1, z, 0, 0, 0);
        accq[t] = z;
    }
    #pragma unroll
    for (int r = 0; r < 4; ++r) {
        float qv[4], ss = 0.f, sd = 0.f;
        #pragma unroll
        for (int t = 0; t < 4; ++t) {
            qv[t] = accq[t][r] + bqc[t];
            ss = fmaf(qv[t], bksc[t], ss);
            sd = fmaf(qv[t], bkdc[t], sd);
        }
        #pragma unroll
        for (int o = 1; o < 16; o <<= 1) { ss += __shfl_xor(ss, o); sd += __shfl_xor(sd, o); }
        int nrow = n0 + quad * 4 + r;
        if (active && c == 0 && nrow < N) { bqs[nrow] = ss; bqd[nrow] = sd; }
        #pragma unroll
        for (int t = 0; t < 4; ++t)
            qtile[w][(quad * 4 + r) * 64 + t * 16 + c] = f2bf(qv[t]);
    }
    __syncthreads();

    const u16* qrow = &qtile[w][c * 64 + quad * 8];
    bf16x8 q0 = *(const bf16x8*)(qrow);
    bf16x8 q1 = *(const bf16x8*)(qrow + 32);
    #pragma unroll
    for (int t = 0; t < 4; ++t) {
        bf16x8 bs0 = *(const bf16x8*)(WksB + ((t * 2 + 0) * 64 + lane) * 8);
        bf16x8 bs1 = *(const bf16x8*)(WksB + ((t * 2 + 1) * 64 + lane) * 8);
        bf16x8 bd0 = *(const bf16x8*)(WkdB + ((t * 2 + 0) * 64 + lane) * 8);
        bf16x8 bd1 = *(const bf16x8*)(WkdB + ((t * 2 + 1) * 64 + lane) * 8);
        f32x4 zs = {0.f, 0.f, 0.f, 0.f}, zd = {0.f, 0.f, 0.f, 0.f};
        zs = __builtin_amdgcn_mfma_f32_16x16x32_bf16(q0, bs0, zs, 0, 0, 0);
        zs = __builtin_amdgcn_mfma_f32_16x16x32_bf16(q1, bs1, zs, 0, 0, 0);
        zd = __builtin_amdgcn_mfma_f32_16x16x32_bf16(q0, bd0, zd, 0, 0, 0);
        zd = __builtin_amdgcn_mfma_f32_16x16x32_bf16(q1, bd1, zd, 0, 0, 0);
        if (active) {
            #pragma unroll
            for (int r = 0; r < 4; ++r) {
                int nrow = n0 + quad * 4 + r;
                if (nrow < N) {
                    long row = (long)nrow * D + t * 16 + c;
                    qksb[row] = f2bf(zs[r]);
                    qkdb[row] = f2bf(zd[r]);
                }
            }
        }
    }
}

// ---- edge pass (MFMA, 16 edges/wave-iter, atomic accumulate, pk-f16 payload)
__global__ __launch_bounds__(256) void edge_pass(
    const int* __restrict__ ei, const float* __restrict__ et, const float* __restrict__ esame,
    const u16* __restrict__ xnb, const u16* __restrict__ WtB,
    const float* __restrict__ Wt, const float* __restrict__ bt,
    const u16* __restrict__ qksb, const u16* __restrict__ qkdb,
    const float* __restrict__ bqs, const float* __restrict__ bqd,
    u16* __restrict__ As, u16* __restrict__ Ad,
    float* __restrict__ den_s, float* __restrict__ den_d, int E)
{
    const int lane = threadIdx.x & 63;
    const int c = lane & 15, quad = lane >> 4;
    const int wave = blockIdx.x * 4 + (threadIdx.x >> 6);
    const int nwaves = gridDim.x * 4;

    bf16x8 bfrag[8];
    #pragma unroll
    for (int f = 0; f < 8; ++f)
        bfrag[f] = *(const bf16x8*)(WtB + (f * 64 + lane) * 8);

    float btc[4], w64c[4], dva[4];
    #pragma unroll
    for (int t = 0; t < 4; ++t) {
        int dim = t * 16 + c;
        btc[t] = bt[dim];
        w64c[t] = Wt[dim * 65 + 64];
        dva[t] = 200.0f * expf(-9.210340371976184f * (float)(2 * (dim >> 1)) * (1.0f / 64.0f));
    }
    const float phoff = (c & 1) ? 1.5707963267948966f : 0.0f;  // cos = sin(x+pi/2)

    for (long e0 = (long)wave * 16; e0 < E; e0 += (long)nwaves * 16) {
        int eL = (int)e0 + c;
        int eLc = eL < E ? eL : E - 1;
        int srcL = ei[eLc];
        int dstL = ei[E + eLc];
        float tL = et[eLc];
        float sameL = esame[eLc];

        const u16* arow = xnb + (long)srcL * D + quad * 8;
        bf16x8 a0 = *(const bf16x8*)(arow);
        bf16x8 a1 = *(const bf16x8*)(arow + 32);

        f32x4 accC[4];
        #pragma unroll
        for (int t = 0; t < 4; ++t) {
            f32x4 z = {0.f, 0.f, 0.f, 0.f};
            z = __builtin_amdgcn_mfma_f32_16x16x32_bf16(a0, bfrag[t * 2 + 0], z, 0, 0, 0);
            z = __builtin_amdgcn_mfma_f32_16x16x32_bf16(a1, bfrag[t * 2 + 1], z, 0, 0, 0);
            accC[t] = z;
        }

        #pragma unroll
        for (int r = 0; r < 4; ++r) {
            int m = quad * 4 + r;
            int dstm = __shfl(dstL, m);
            float tm = __shfl(tL, m);
            bool same = __shfl(sameL, m) > 0.5f;
            bool valid = (e0 + m) < E;

            const u16* qsel = same ? qksb : qkdb;
            float xtv[4], p = 0.f;
            #pragma unroll
            for (int t = 0; t < 4; ++t) {
                float v = gelu_tanh(accC[t][r] + fmaf(tm, w64c[t], btc[t]));
                v += __sinf(fmaf(tm, dva[t], phoff));
                xtv[t] = v;
                p = fmaf(v, bf2f(qsel[(long)dstm * D + t * 16 + c]), p);
            }
            #pragma unroll
            for (int o = 1; o < 16; o <<= 1) p += __shfl_xor(p, o);
            float ex = valid ? __expf((p + (same ? bqs[dstm] : bqd[dstm])) * 0.125f) : 0.0f;
            if (c == 0) atomicAdd(same ? &den_s[dstm] : &den_d[dstm], ex);

            u16* Asel = same ? As : Ad;
            #pragma unroll
            for (int t = 0; t < 4; ++t) {
                float v = ex * xtv[t];
                float po = __shfl_xor(v, 1);
                if (((t ^ c) & 1) == 0) {       // even lanes emit even t, odd lanes odd t
                    float lo = (c & 1) ? po : v;
                    float hi = (c & 1) ? v : po;
                    atomic_pk_add_f16(&Asel[(long)dstm * D + t * 16 + (c & ~1)], lo, hi);
                }
            }
        }
    }
}

// ---- node post, MFMA: aggr = inv*(As@Wvs^T + Ad@Wvd^T) + (dens*inv)*bvs + (dend*inv)*bvd
//      out = x + gelu(aggr)      (16 nodes per wave; As/Ad are f16)
__global__ __launch_bounds__(256) void vgemm(
    const float* __restrict__ x, const u16* __restrict__ As, const u16* __restrict__ Ad,
    const float* __restrict__ den_s, const float* __restrict__ den_d,
    const u16* __restrict__ WvsB, const u16* __restrict__ WvdB,
    const float* __restrict__ bvs, const float* __restrict__ bvd,
    float* __restrict__ out, int N)
{
    const int lane = threadIdx.x & 63;
    const int c = lane & 15, quad = lane >> 4;
    const int wave = blockIdx.x * 4 + (threadIdx.x >> 6);
    const int n0r = wave * 16;
    if (n0r >= N) return;
    const int n0 = n0r;
    const int rowA = (n0 + c < N) ? n0 + c : N - 1;

    float bvsc[4], bvdc[4];
    #pragma unroll
    for (int t = 0; t < 4; ++t) { bvsc[t] = bvs[t * 16 + c]; bvdc[t] = bvd[t * 16 + c]; }

    const u16* srow = As + (long)rowA * D + quad * 8;
    const u16* drow = Ad + (long)rowA * D + quad * 8;
    f16x8 s0 = *(const f16x8*)(srow);
    f16x8 s1 = *(const f16x8*)(srow + 32);
    f16x8 d0 = *(const f16x8*)(drow);
    f16x8 d1 = *(const f16x8*)(drow + 32);

    f32x4 acc[4];
    #pragma unroll
    for (int t = 0; t < 4; ++t) {
        f16x8 bs0 = *(const f16x8*)(WvsB + ((t * 2 + 0) * 64 + lane) * 8);
        f16x8 bs1 = *(const f16x8*)(WvsB + ((t * 2 + 1) * 64 + lane) * 8);
        f16x8 bd0 = *(const f16x8*)(WvdB + ((t * 2 + 0) * 64 + lane) * 8);
        f16x8 bd1 = *(const f16x8*)(WvdB + ((t * 2 + 1) * 64 + lane) * 8);
        f32x4 z = {0.f, 0.f, 0.f, 0.f};
        z = __builtin_amdgcn_mfma_f32_16x16x32_f16(s0, bs0, z, 0, 0, 0);
        z = __builtin_amdgcn_mfma_f32_16x16x32_f16(s1, bs1, z, 0, 0, 0);
        z = __builtin_amdgcn_mfma_f32_16x16x32_f16(d0, bd0, z, 0, 0, 0);
        z = __builtin_amdgcn_mfma_f32_16x16x32_f16(d1, bd1, z, 0, 0, 0);
        acc[t] = z;
    }

    #pragma unroll
    for (int r = 0; r < 4; ++r) {
        int n = n0 + quad * 4 + r;
        if (n >= N) continue;
        float ds = den_s[n], dd = den_d[n];
        float inv = 1.0f / (ds + dd + 1e-16f);
        float fs = ds * inv, fd = dd * inv;
        #pragma unroll
        for (int t = 0; t < 4; ++t) {
            long idx = (long)n * D + t * 16 + c;
            float o = fmaf(acc[t][r], inv, fmaf(fs, bvsc[t], fd * bvdc[t]));
            out[idx] = x[idx] + gelu_erf(o);
        }
    }
}

extern "C" void kernel_launch(void* const* d_in, const int* in_sizes, int n_in,
                              void* d_out, int out_size, void* d_ws, size_t ws_size,
                              hipStream_t stream) {
    const float* x        = (const float*)d_in[0];
    const int*   ei       = (const int*)d_in[1];
    const float* et       = (const float*)d_in[2];
    const float* esame    = (const float*)d_in[4];
    const float* ln_gamma = (const float*)d_in[5];
    const float* ln_beta  = (const float*)d_in[6];
    const float* Wt  = (const float*)d_in[7];
    const float* bt  = (const float*)d_in[8];
    const float* Wq  = (const float*)d_in[9];
    const float* bq  = (const float*)d_in[10];
    const float* Wks = (const float*)d_in[11];
    const float* bks = (const float*)d_in[12];
    const float* Wkd = (const float*)d_in[13];
    const float* bkd = (const float*)d_in[14];
    const float* Wvs = (const float*)d_in[15];
    const float* bvs = (const float*)d_in[16];
    const float* Wvd = (const float*)d_in[17];
    const float* bvd = (const float*)d_in[18];
    float* out = (float*)d_out;

    const int N = in_sizes[0] / D;   // 50000
    const int E = in_sizes[2];       // 800000

    // workspace layout (As,Ad,dens,dend contiguous for one memset)
    u16* As = (u16*)d_ws;                 // N*64 f16
    u16* Ad = As + (long)N * D;           // N*64 f16
    float* dens = (float*)(Ad + (long)N * D);
    float* dend = dens + N;
    float* bqs = dend + N;
    float* bqd = bqs + N;
    u16* xnb  = (u16*)(bqd + N);          // N*64 bf16
    u16* qksb = xnb + (long)N * D;        // N*64 bf16
    u16* qkdb = qksb + (long)N * D;       // N*64 bf16
    u16* WtB  = qkdb + (long)N * D;       // 4096 each
    u16* WqB  = WtB + 4096;
    u16* WksB = WqB + 4096;
    u16* WkdB = WksB + 4096;
    u16* WvsB = WkdB + 4096;
    u16* WvdB = WvsB + 4096;

    hipMemsetAsync(As, 0, (size_t)N * D * 2 * 2 + (size_t)N * 2 * 4, stream);

    prep_weights<<<1, 384, 0, stream>>>(Wt, Wq, Wks, Wkd, Wvs, Wvd,
                                        WtB, WqB, WksB, WkdB, WvsB, WvdB);
    ln_kernel<<<512, 256, 0, stream>>>(x, ln_gamma, ln_beta, xnb, N);
    const int nblk16 = ((N + 15) / 16 + 3) / 4;
    qgemm<<<nblk16, 256, 0, stream>>>(xnb, WqB, WksB, WkdB, bq, bks, bkd,
                                      qksb, qkdb, bqs, bqd, N);
    edge_pass<<<2048, 256, 0, stream>>>(ei, et, esame, xnb, WtB, Wt, bt,
                                        qksb, qkdb, bqs, bqd, As, Ad, dens, dend, E);
    vgemm<<<nblk16, 256, 0, stream>>>(x, As, Ad, dens, dend, WvsB, WvdB, bvs, bvd, out, N);
}

// Round 5
// 343.094 us; speedup vs baseline: 1.9486x; 1.0967x over previous
//
#include <hip/hip_runtime.h>
#include <hip/hip_bf16.h>
#include <math.h>

#define D 64

typedef __attribute__((ext_vector_type(8))) short bf16x8;
typedef __attribute__((ext_vector_type(8))) _Float16 f16x8;
typedef __attribute__((ext_vector_type(8))) unsigned short u16x8;
typedef __attribute__((ext_vector_type(4))) float f32x4;
typedef unsigned short u16;

__device__ __forceinline__ float gelu_erf(float x) {
    return 0.5f * x * (1.0f + erff(x * 0.70710678118654752f));
}
// branchless tanh-gelu: max err ~3e-3 vs erf-gelu
__device__ __forceinline__ float gelu_tanh(float x) {
    float u = x * fmaf(x * x, 0.035677408136f, 0.7978845608028654f);
    float e = __expf(2.0f * u);
    float th = 1.0f - 2.0f / (e + 1.0f);
    return 0.5f * x * (1.0f + th);
}
__device__ __forceinline__ u16 f2bf(float v) {
    __hip_bfloat16 h = __float2bfloat16(v);
    return *(u16*)&h;
}
__device__ __forceinline__ float bf2f(u16 v) {
    return __uint_as_float(((unsigned int)v) << 16);
}
__device__ __forceinline__ u16 f2h(float v) {
    _Float16 h = (_Float16)v;
    return __builtin_bit_cast(u16, h);
}
// packed f16 atomic add (device scope). volatile keeps the side effect; no
// "memory" clobber so the scheduler may hoist later loads above the atomic.
__device__ __forceinline__ void atomic_pk_add_f16(u16* addr, float lo, float hi) {
    unsigned int p = (unsigned int)f2h(lo) | ((unsigned int)f2h(hi) << 16);
    asm volatile("global_atomic_pk_add_f16 %0, %1, off sc1" :: "v"(addr), "v"(p));
}

// ---- pack weights into MFMA B-fragments (frag f = ntile*2+kk; lane holds
// B[k=kk*32+quad*8+j][n=ntile*16+c]).  48 blocks: (weight, frag).
__global__ void prep_weights(const float* __restrict__ Wt, const float* __restrict__ Wq,
                             const float* __restrict__ Wks, const float* __restrict__ Wkd,
                             const float* __restrict__ Wvs, const float* __restrict__ Wvd,
                             u16* __restrict__ WtB, u16* __restrict__ WqB,
                             u16* __restrict__ WksB, u16* __restrict__ WkdB,
                             u16* __restrict__ WvsB, u16* __restrict__ WvdB)
{
    int lane = threadIdx.x & 63;
    int wsel = blockIdx.x >> 3, f = blockIdx.x & 7;
    int c = lane & 15, quad = lane >> 4;
    int nt = f >> 1, kk = f & 1;
    for (int j = 0; j < 8; ++j) {
        int n = nt * 16 + c, k = kk * 32 + quad * 8 + j;
        float v; u16* dp; bool half16 = false;
        switch (wsel) {
            case 0: v = Wt[n * 65 + k];  dp = WtB;  break;
            case 1: v = Wq[n * 64 + k];  dp = WqB;  break;
            case 2: v = Wks[k * 64 + n]; dp = WksB; break;
            case 3: v = Wkd[k * 64 + n]; dp = WkdB; break;
            case 4: v = Wvs[n * 64 + k]; dp = WvsB; half16 = true; break;
            default: v = Wvd[n * 64 + k]; dp = WvdB; half16 = true; break;
        }
        dp[(f * 64 + lane) * 8 + j] = half16 ? f2h(v) : f2bf(v);
    }
}

// ---- fused LN + q-chain (all-MFMA): xn = LN(x) -> xnb (bf16) + A-frags;
//      q = xn@Wq^T + bq ; qks = q@Wks ; qkd = q@Wkd (bf16, LDS-staged stores);
//      bqs = q.bks ; bqd = q.bkd      (16 nodes per wave)
__global__ __launch_bounds__(256) void qgemm(
    const float* __restrict__ x, const float* __restrict__ gamma, const float* __restrict__ beta,
    const u16* __restrict__ WqB, const u16* __restrict__ WksB, const u16* __restrict__ WkdB,
    const float* __restrict__ bq, const float* __restrict__ bks, const float* __restrict__ bkd,
    u16* __restrict__ xnb, u16* __restrict__ qksb, u16* __restrict__ qkdb,
    float* __restrict__ bqs, float* __restrict__ bqd, int N)
{
    __shared__ u16 qtile[4][16 * 64];
    __shared__ u16 stile[4][2][16 * 64];
    const int lane = threadIdx.x & 63;
    const int c = lane & 15, quad = lane >> 4;
    const int w = threadIdx.x >> 6;
    const int wave = blockIdx.x * 4 + w;
    const int n0r = wave * 16;
    const bool active = n0r < N;
    const int n0 = active ? n0r : 0;
    const int rowA = (n0 + c < N) ? n0 + c : N - 1;

    // ---- fused LayerNorm in A-fragment layout ----
    const float* xrow = x + (long)rowA * D;
    f32x4 xa = *(const f32x4*)(xrow + quad * 8);
    f32x4 xb = *(const f32x4*)(xrow + quad * 8 + 4);
    f32x4 xc = *(const f32x4*)(xrow + 32 + quad * 8);
    f32x4 xd = *(const f32x4*)(xrow + 32 + quad * 8 + 4);
    float s = 0.f, s2 = 0.f;
    #pragma unroll
    for (int j = 0; j < 4; ++j) {
        s += xa[j] + xb[j] + xc[j] + xd[j];
        s2 += xa[j] * xa[j] + xb[j] * xb[j] + xc[j] * xc[j] + xd[j] * xd[j];
    }
    s += __shfl_xor(s, 16);  s += __shfl_xor(s, 32);
    s2 += __shfl_xor(s2, 16); s2 += __shfl_xor(s2, 32);
    float mu = s * (1.0f / 64.0f);
    float var = s2 * (1.0f / 64.0f) - mu * mu;
    float rinv = rsqrtf(var + 1e-5f);
    f32x4 ga = *(const f32x4*)(gamma + quad * 8);
    f32x4 gb = *(const f32x4*)(gamma + quad * 8 + 4);
    f32x4 gc = *(const f32x4*)(gamma + 32 + quad * 8);
    f32x4 gd = *(const f32x4*)(gamma + 32 + quad * 8 + 4);
    f32x4 ba = *(const f32x4*)(beta + quad * 8);
    f32x4 bb = *(const f32x4*)(beta + quad * 8 + 4);
    f32x4 bc = *(const f32x4*)(beta + 32 + quad * 8);
    f32x4 bd = *(const f32x4*)(beta + 32 + quad * 8 + 4);
    bf16x8 a0, a1;
    #pragma unroll
    for (int j = 0; j < 4; ++j) {
        a0[j]     = (short)f2bf(fmaf((xa[j] - mu) * rinv, ga[j], ba[j]));
        a0[4 + j] = (short)f2bf(fmaf((xb[j] - mu) * rinv, gb[j], bb[j]));
        a1[j]     = (short)f2bf(fmaf((xc[j] - mu) * rinv, gc[j], bc[j]));
        a1[4 + j] = (short)f2bf(fmaf((xd[j] - mu) * rinv, gd[j], bd[j]));
    }
    *(bf16x8*)(xnb + (long)rowA * D + quad * 8) = a0;
    *(bf16x8*)(xnb + (long)rowA * D + 32 + quad * 8) = a1;

    float bqc[4], bksc[4], bkdc[4];
    #pragma unroll
    for (int t = 0; t < 4; ++t) {
        bqc[t] = bq[t * 16 + c]; bksc[t] = bks[t * 16 + c]; bkdc[t] = bkd[t * 16 + c];
    }

    // GEMM1: q
    f32x4 accq[4];
    #pragma unroll
    for (int t = 0; t < 4; ++t) {
        bf16x8 b0 = *(const bf16x8*)(WqB + ((t * 2 + 0) * 64 + lane) * 8);
        bf16x8 b1 = *(const bf16x8*)(WqB + ((t * 2 + 1) * 64 + lane) * 8);
        f32x4 z = {0.f, 0.f, 0.f, 0.f};
        z = __builtin_amdgcn_mfma_f32_16x16x32_bf16(a0, b0, z, 0, 0, 0);
        z = __builtin_amdgcn_mfma_f32_16x16x32_bf16(a1, b1, z, 0, 0, 0);
        accq[t] = z;
    }
    #pragma unroll
    for (int r = 0; r < 4; ++r) {
        float qv[4], ss = 0.f, sd = 0.f;
        #pragma unroll
        for (int t = 0; t < 4; ++t) {
            qv[t] = accq[t][r] + bqc[t];
            ss = fmaf(qv[t], bksc[t], ss);
            sd = fmaf(qv[t], bkdc[t], sd);
        }
        #pragma unroll
        for (int o = 1; o < 16; o <<= 1) { ss += __shfl_xor(ss, o); sd += __shfl_xor(sd, o); }
        int nrow = n0 + quad * 4 + r;
        if (active && c == 0 && nrow < N) { bqs[nrow] = ss; bqd[nrow] = sd; }
        #pragma unroll
        for (int t = 0; t < 4; ++t)
            qtile[w][(quad * 4 + r) * 64 + t * 16 + c] = f2bf(qv[t]);
    }
    __syncthreads();

    // GEMM2: qks / qkd -> LDS stage -> coalesced b128 stores
    const u16* qrow = &qtile[w][c * 64 + quad * 8];
    bf16x8 q0 = *(const bf16x8*)(qrow);
    bf16x8 q1 = *(const bf16x8*)(qrow + 32);
    #pragma unroll
    for (int t = 0; t < 4; ++t) {
        bf16x8 bs0 = *(const bf16x8*)(WksB + ((t * 2 + 0) * 64 + lane) * 8);
        bf16x8 bs1 = *(const bf16x8*)(WksB + ((t * 2 + 1) * 64 + lane) * 8);
        bf16x8 bd0 = *(const bf16x8*)(WkdB + ((t * 2 + 0) * 64 + lane) * 8);
        bf16x8 bd1 = *(const bf16x8*)(WkdB + ((t * 2 + 1) * 64 + lane) * 8);
        f32x4 zs = {0.f, 0.f, 0.f, 0.f}, zd = {0.f, 0.f, 0.f, 0.f};
        zs = __builtin_amdgcn_mfma_f32_16x16x32_bf16(q0, bs0, zs, 0, 0, 0);
        zs = __builtin_amdgcn_mfma_f32_16x16x32_bf16(q1, bs1, zs, 0, 0, 0);
        zd = __builtin_amdgcn_mfma_f32_16x16x32_bf16(q0, bd0, zd, 0, 0, 0);
        zd = __builtin_amdgcn_mfma_f32_16x16x32_bf16(q1, bd1, zd, 0, 0, 0);
        #pragma unroll
        for (int r = 0; r < 4; ++r) {
            stile[w][0][(quad * 4 + r) * 64 + t * 16 + c] = f2bf(zs[r]);
            stile[w][1][(quad * 4 + r) * 64 + t * 16 + c] = f2bf(zd[r]);
        }
    }
    if (active) {
        if (n0 + 16 <= N) {
            const u16x8* s0p = (const u16x8*)&stile[w][0][0];
            const u16x8* s1p = (const u16x8*)&stile[w][1][0];
            u16x8* d0p = (u16x8*)(qksb + (long)n0 * D);
            u16x8* d1p = (u16x8*)(qkdb + (long)n0 * D);
            d0p[2 * lane] = s0p[2 * lane];
            d0p[2 * lane + 1] = s0p[2 * lane + 1];
            d1p[2 * lane] = s1p[2 * lane];
            d1p[2 * lane + 1] = s1p[2 * lane + 1];
        } else {
            for (int i = lane; i < (N - n0) * D; i += 64) {
                qksb[(long)n0 * D + i] = stile[w][0][i];
                qkdb[(long)n0 * D + i] = stile[w][1][i];
            }
        }
    }
}

// ---- edge pass: MFMA, TWO 16-edge tiles per loop iteration (ILP), pk-f16 atomics
__global__ __launch_bounds__(256) void edge_pass(
    const int* __restrict__ ei, const float* __restrict__ et, const float* __restrict__ esame,
    const u16* __restrict__ xnb, const u16* __restrict__ WtB,
    const float* __restrict__ Wt, const float* __restrict__ bt,
    const u16* __restrict__ qksb, const u16* __restrict__ qkdb,
    const float* __restrict__ bqs, const float* __restrict__ bqd,
    u16* __restrict__ As, u16* __restrict__ Ad,
    float* __restrict__ den_s, float* __restrict__ den_d, int E)
{
    const int lane = threadIdx.x & 63;
    const int c = lane & 15, quad = lane >> 4;
    const int wave = blockIdx.x * 4 + (threadIdx.x >> 6);
    const int nwaves = gridDim.x * 4;

    bf16x8 bfrag[8];
    #pragma unroll
    for (int f = 0; f < 8; ++f)
        bfrag[f] = *(const bf16x8*)(WtB + (f * 64 + lane) * 8);

    float btc[4], w64c[4], dva[4];
    #pragma unroll
    for (int t = 0; t < 4; ++t) {
        int dim = t * 16 + c;
        btc[t] = bt[dim];
        w64c[t] = Wt[dim * 65 + 64];
        dva[t] = 200.0f * expf(-9.210340371976184f * (float)(2 * (dim >> 1)) * (1.0f / 64.0f));
    }
    const float phoff = (c & 1) ? 1.5707963267948966f : 0.0f;  // cos = sin(x+pi/2)

    auto epilogue = [&](long e0, const f32x4* accC, int dstL, float tL, float sameL) {
        #pragma unroll
        for (int r = 0; r < 4; ++r) {
            int m = quad * 4 + r;
            int dstm = __shfl(dstL, m);
            float tm = __shfl(tL, m);
            bool same = __shfl(sameL, m) > 0.5f;
            bool valid = (e0 + m) < E;

            const u16* qsel = same ? qksb : qkdb;
            float xtv[4], p = 0.f;
            #pragma unroll
            for (int t = 0; t < 4; ++t) {
                float v = gelu_tanh(accC[t][r] + fmaf(tm, w64c[t], btc[t]));
                v += __sinf(fmaf(tm, dva[t], phoff));
                xtv[t] = v;
                p = fmaf(v, bf2f(qsel[(long)dstm * D + t * 16 + c]), p);
            }
            #pragma unroll
            for (int o = 1; o < 16; o <<= 1) p += __shfl_xor(p, o);
            float ex = valid ? __expf((p + (same ? bqs[dstm] : bqd[dstm])) * 0.125f) : 0.0f;
            if (c == 0) atomicAdd(same ? &den_s[dstm] : &den_d[dstm], ex);

            u16* Asel = same ? As : Ad;
            #pragma unroll
            for (int t = 0; t < 4; ++t) {
                float v = ex * xtv[t];
                float po = __shfl_xor(v, 1);
                if (((t ^ c) & 1) == 0) {       // even lanes emit even t, odd lanes odd t
                    float lo = (c & 1) ? po : v;
                    float hi = (c & 1) ? v : po;
                    atomic_pk_add_f16(&Asel[(long)dstm * D + t * 16 + (c & ~1)], lo, hi);
                }
            }
        }
    };

    for (long base = (long)wave * 32; base < E; base += (long)nwaves * 32) {
        long eA0 = base, eB0 = base + 16;
        int eA = (int)eA0 + c;  int eAc = eA < E ? eA : E - 1;
        int eB = (int)eB0 + c;  int eBc = eB < E ? eB : E - 1;
        int srcA = ei[eAc], dstA = ei[E + eAc];
        float tA = et[eAc], sameA = esame[eAc];
        int srcB = ei[eBc], dstB = ei[E + eBc];
        float tB = et[eBc], sameB = esame[eBc];

        const u16* arA = xnb + (long)srcA * D + quad * 8;
        bf16x8 a0A = *(const bf16x8*)(arA);
        bf16x8 a1A = *(const bf16x8*)(arA + 32);
        const u16* arB = xnb + (long)srcB * D + quad * 8;
        bf16x8 a0B = *(const bf16x8*)(arB);
        bf16x8 a1B = *(const bf16x8*)(arB + 32);

        f32x4 accA[4], accB[4];
        #pragma unroll
        for (int t = 0; t < 4; ++t) {
            f32x4 zA = {0.f, 0.f, 0.f, 0.f};
            zA = __builtin_amdgcn_mfma_f32_16x16x32_bf16(a0A, bfrag[t * 2 + 0], zA, 0, 0, 0);
            zA = __builtin_amdgcn_mfma_f32_16x16x32_bf16(a1A, bfrag[t * 2 + 1], zA, 0, 0, 0);
            accA[t] = zA;
            f32x4 zB = {0.f, 0.f, 0.f, 0.f};
            zB = __builtin_amdgcn_mfma_f32_16x16x32_bf16(a0B, bfrag[t * 2 + 0], zB, 0, 0, 0);
            zB = __builtin_amdgcn_mfma_f32_16x16x32_bf16(a1B, bfrag[t * 2 + 1], zB, 0, 0, 0);
            accB[t] = zB;
        }

        epilogue(eA0, accA, dstA, tA, sameA);
        if (eB0 < E) epilogue(eB0, accB, dstB, tB, sameB);
    }
}

// ---- node post, MFMA: aggr = inv*(As@Wvs^T + Ad@Wvd^T) + (dens*inv)*bvs + (dend*inv)*bvd
//      out = x + gelu(aggr)      (16 nodes per wave; As/Ad are f16)
__global__ __launch_bounds__(256) void vgemm(
    const float* __restrict__ x, const u16* __restrict__ As, const u16* __restrict__ Ad,
    const float* __restrict__ den_s, const float* __restrict__ den_d,
    const u16* __restrict__ WvsB, const u16* __restrict__ WvdB,
    const float* __restrict__ bvs, const float* __restrict__ bvd,
    float* __restrict__ out, int N)
{
    const int lane = threadIdx.x & 63;
    const int c = lane & 15, quad = lane >> 4;
    const int wave = blockIdx.x * 4 + (threadIdx.x >> 6);
    const int n0r = wave * 16;
    if (n0r >= N) return;
    const int n0 = n0r;
    const int rowA = (n0 + c < N) ? n0 + c : N - 1;

    float bvsc[4], bvdc[4];
    #pragma unroll
    for (int t = 0; t < 4; ++t) { bvsc[t] = bvs[t * 16 + c]; bvdc[t] = bvd[t * 16 + c]; }

    const u16* srow = As + (long)rowA * D + quad * 8;
    const u16* drow = Ad + (long)rowA * D + quad * 8;
    f16x8 s0 = *(const f16x8*)(srow);
    f16x8 s1 = *(const f16x8*)(srow + 32);
    f16x8 d0 = *(const f16x8*)(drow);
    f16x8 d1 = *(const f16x8*)(drow + 32);

    f32x4 acc[4];
    #pragma unroll
    for (int t = 0; t < 4; ++t) {
        f16x8 bs0 = *(const f16x8*)(WvsB + ((t * 2 + 0) * 64 + lane) * 8);
        f16x8 bs1 = *(const f16x8*)(WvsB + ((t * 2 + 1) * 64 + lane) * 8);
        f16x8 bd0 = *(const f16x8*)(WvdB + ((t * 2 + 0) * 64 + lane) * 8);
        f16x8 bd1 = *(const f16x8*)(WvdB + ((t * 2 + 1) * 64 + lane) * 8);
        f32x4 z = {0.f, 0.f, 0.f, 0.f};
        z = __builtin_amdgcn_mfma_f32_16x16x32_f16(s0, bs0, z, 0, 0, 0);
        z = __builtin_amdgcn_mfma_f32_16x16x32_f16(s1, bs1, z, 0, 0, 0);
        z = __builtin_amdgcn_mfma_f32_16x16x32_f16(d0, bd0, z, 0, 0, 0);
        z = __builtin_amdgcn_mfma_f32_16x16x32_f16(d1, bd1, z, 0, 0, 0);
        acc[t] = z;
    }

    #pragma unroll
    for (int r = 0; r < 4; ++r) {
        int n = n0 + quad * 4 + r;
        if (n >= N) continue;
        float ds = den_s[n], dd = den_d[n];
        float inv = 1.0f / (ds + dd + 1e-16f);
        float fs = ds * inv, fd = dd * inv;
        #pragma unroll
        for (int t = 0; t < 4; ++t) {
            long idx = (long)n * D + t * 16 + c;
            float o = fmaf(acc[t][r], inv, fmaf(fs, bvsc[t], fd * bvdc[t]));
            out[idx] = x[idx] + gelu_erf(o);
        }
    }
}

extern "C" void kernel_launch(void* const* d_in, const int* in_sizes, int n_in,
                              void* d_out, int out_size, void* d_ws, size_t ws_size,
                              hipStream_t stream) {
    const float* x        = (const float*)d_in[0];
    const int*   ei       = (const int*)d_in[1];
    const float* et       = (const float*)d_in[2];
    const float* esame    = (const float*)d_in[4];
    const float* ln_gamma = (const float*)d_in[5];
    const float* ln_beta  = (const float*)d_in[6];
    const float* Wt  = (const float*)d_in[7];
    const float* bt  = (const float*)d_in[8];
    const float* Wq  = (const float*)d_in[9];
    const float* bq  = (const float*)d_in[10];
    const float* Wks = (const float*)d_in[11];
    const float* bks = (const float*)d_in[12];
    const float* Wkd = (const float*)d_in[13];
    const float* bkd = (const float*)d_in[14];
    const float* Wvs = (const float*)d_in[15];
    const float* bvs = (const float*)d_in[16];
    const float* Wvd = (const float*)d_in[17];
    const float* bvd = (const float*)d_in[18];
    float* out = (float*)d_out;

    const int N = in_sizes[0] / D;   // 50000
    const int E = in_sizes[2];       // 800000

    // workspace layout (As,Ad,dens,dend contiguous for one memset)
    u16* As = (u16*)d_ws;                 // N*64 f16
    u16* Ad = As + (long)N * D;           // N*64 f16
    float* dens = (float*)(Ad + (long)N * D);
    float* dend = dens + N;
    float* bqs = dend + N;
    float* bqd = bqs + N;
    u16* xnb  = (u16*)(bqd + N);          // N*64 bf16
    u16* qksb = xnb + (long)N * D;        // N*64 bf16
    u16* qkdb = qksb + (long)N * D;       // N*64 bf16
    u16* WtB  = qkdb + (long)N * D;       // 4096 each
    u16* WqB  = WtB + 4096;
    u16* WksB = WqB + 4096;
    u16* WkdB = WksB + 4096;
    u16* WvsB = WkdB + 4096;
    u16* WvdB = WvsB + 4096;

    hipMemsetAsync(As, 0, (size_t)N * D * 2 * 2 + (size_t)N * 2 * 4, stream);

    prep_weights<<<48, 64, 0, stream>>>(Wt, Wq, Wks, Wkd, Wvs, Wvd,
                                        WtB, WqB, WksB, WkdB, WvsB, WvdB);
    const int nblk16 = ((N + 15) / 16 + 3) / 4;
    qgemm<<<nblk16, 256, 0, stream>>>(x, ln_gamma, ln_beta, WqB, WksB, WkdB,
                                      bq, bks, bkd, xnb, qksb, qkdb, bqs, bqd, N);
    edge_pass<<<2048, 256, 0, stream>>>(ei, et, esame, xnb, WtB, Wt, bt,
                                        qksb, qkdb, bqs, bqd, As, Ad, dens, dend, E);
    vgemm<<<nblk16, 256, 0, stream>>>(x, As, Ad, dens, dend, WvsB, WvdB, bvs, bvd, out, N);
}

// Round 6
// 335.883 us; speedup vs baseline: 1.9904x; 1.0215x over previous
//
#include <hip/hip_runtime.h>
#include <hip/hip_bf16.h>
#include <math.h>

#define D 64

typedef __attribute__((ext_vector_type(8))) short bf16x8;
typedef __attribute__((ext_vector_type(8))) _Float16 f16x8;
typedef __attribute__((ext_vector_type(8))) unsigned short u16x8;
typedef __attribute__((ext_vector_type(4))) float f32x4;
typedef unsigned short u16;

__device__ __forceinline__ float gelu_erf(float x) {
    return 0.5f * x * (1.0f + erff(x * 0.70710678118654752f));
}
// branchless tanh-gelu: max err ~3e-3 vs erf-gelu
__device__ __forceinline__ float gelu_tanh(float x) {
    float u = x * fmaf(x * x, 0.035677408136f, 0.7978845608028654f);
    float e = __expf(2.0f * u);
    float th = 1.0f - 2.0f / (e + 1.0f);
    return 0.5f * x * (1.0f + th);
}
__device__ __forceinline__ u16 f2bf(float v) {
    __hip_bfloat16 h = __float2bfloat16(v);
    return *(u16*)&h;
}
__device__ __forceinline__ float bf2f(u16 v) {
    return __uint_as_float(((unsigned int)v) << 16);
}
__device__ __forceinline__ u16 f2h(float v) {
    _Float16 h = (_Float16)v;
    return __builtin_bit_cast(u16, h);
}
// packed f16 atomic add (device scope), no "memory" clobber so later loads can hoist.
__device__ __forceinline__ void atomic_pk_add_f16(u16* addr, float lo, float hi) {
    unsigned int p = (unsigned int)f2h(lo) | ((unsigned int)f2h(hi) << 16);
    asm volatile("global_atomic_pk_add_f16 %0, %1, off sc1" :: "v"(addr), "v"(p));
}

// dim permutation: pos p holds dim pi(p) = (p&3)*16 + (p>>2)   (dim t*16+c <-> pos c*4+t)
__device__ __forceinline__ int pi_perm(int p) { return ((p & 3) << 4) | (p >> 2); }

// ---- pack weights into MFMA B-fragments (frag f = ntile*2+kk; lane holds
// B[k=kk*32+quad*8+j][n=ntile*16+c]).  48 blocks: (weight, frag).
// Wvs/Wvd additionally get the k-axis pi-permuted (to match permuted As/Ad).
__global__ void prep_weights(const float* __restrict__ Wt, const float* __restrict__ Wq,
                             const float* __restrict__ Wks, const float* __restrict__ Wkd,
                             const float* __restrict__ Wvs, const float* __restrict__ Wvd,
                             u16* __restrict__ WtB, u16* __restrict__ WqB,
                             u16* __restrict__ WksB, u16* __restrict__ WkdB,
                             u16* __restrict__ WvsB, u16* __restrict__ WvdB)
{
    int lane = threadIdx.x & 63;
    int wsel = blockIdx.x >> 3, f = blockIdx.x & 7;
    int c = lane & 15, quad = lane >> 4;
    int nt = f >> 1, kk = f & 1;
    for (int j = 0; j < 8; ++j) {
        int n = nt * 16 + c, k = kk * 32 + quad * 8 + j;
        float v; u16* dp; bool half16 = false;
        switch (wsel) {
            case 0: v = Wt[n * 65 + k];  dp = WtB;  break;
            case 1: v = Wq[n * 64 + k];  dp = WqB;  break;
            case 2: v = Wks[k * 64 + n]; dp = WksB; break;
            case 3: v = Wkd[k * 64 + n]; dp = WkdB; break;
            case 4: v = Wvs[n * 64 + pi_perm(k)]; dp = WvsB; half16 = true; break;
            default: v = Wvd[n * 64 + pi_perm(k)]; dp = WvdB; half16 = true; break;
        }
        dp[(f * 64 + lane) * 8 + j] = half16 ? f2h(v) : f2bf(v);
    }
}

// ---- fused LN + q-chain (all-MFMA): xn = LN(x) -> xnb (bf16) + A-frags;
//      q = xn@Wq^T + bq ; qks/qkd = q@Wk{s,d} stored PI-PERMUTED bf16;
//      bqs = q.bks ; bqd = q.bkd.  Also zero-inits As/Ad/dens/dend rows.
__global__ __launch_bounds__(256) void qgemm(
    const float* __restrict__ x, const float* __restrict__ gamma, const float* __restrict__ beta,
    const u16* __restrict__ WqB, const u16* __restrict__ WksB, const u16* __restrict__ WkdB,
    const float* __restrict__ bq, const float* __restrict__ bks, const float* __restrict__ bkd,
    u16* __restrict__ xnb, u16* __restrict__ qksb, u16* __restrict__ qkdb,
    float* __restrict__ bqs, float* __restrict__ bqd,
    u16* __restrict__ As, u16* __restrict__ Ad,
    float* __restrict__ dens, float* __restrict__ dend, int N)
{
    __shared__ u16 qtile[4][16 * 64];
    __shared__ u16 stile[4][2][16 * 64];
    const int lane = threadIdx.x & 63;
    const int c = lane & 15, quad = lane >> 4;
    const int w = threadIdx.x >> 6;
    const int wave = blockIdx.x * 4 + w;
    const int n0r = wave * 16;
    const bool active = n0r < N;
    const int n0 = active ? n0r : 0;
    const int rowA = (n0 + c < N) ? n0 + c : N - 1;

    // zero accumulators for this wave's rows
    if (active) {
        int nrows = min(16, N - n0);
        u16x8 z8 = {0, 0, 0, 0, 0, 0, 0, 0};
        u16x8* za = (u16x8*)(As + (long)n0 * D);
        u16x8* zd = (u16x8*)(Ad + (long)n0 * D);
        for (int i = lane; i < nrows * 8; i += 64) { za[i] = z8; zd[i] = z8; }
        for (int i = lane; i < nrows; i += 64) { dens[n0 + i] = 0.f; dend[n0 + i] = 0.f; }
    }

    // ---- fused LayerNorm in A-fragment layout ----
    const float* xrow = x + (long)rowA * D;
    f32x4 xa = *(const f32x4*)(xrow + quad * 8);
    f32x4 xb = *(const f32x4*)(xrow + quad * 8 + 4);
    f32x4 xc = *(const f32x4*)(xrow + 32 + quad * 8);
    f32x4 xd = *(const f32x4*)(xrow + 32 + quad * 8 + 4);
    float s = 0.f, s2 = 0.f;
    #pragma unroll
    for (int j = 0; j < 4; ++j) {
        s += xa[j] + xb[j] + xc[j] + xd[j];
        s2 += xa[j] * xa[j] + xb[j] * xb[j] + xc[j] * xc[j] + xd[j] * xd[j];
    }
    s += __shfl_xor(s, 16);  s += __shfl_xor(s, 32);
    s2 += __shfl_xor(s2, 16); s2 += __shfl_xor(s2, 32);
    float mu = s * (1.0f / 64.0f);
    float var = s2 * (1.0f / 64.0f) - mu * mu;
    float rinv = rsqrtf(var + 1e-5f);
    f32x4 ga = *(const f32x4*)(gamma + quad * 8);
    f32x4 gb = *(const f32x4*)(gamma + quad * 8 + 4);
    f32x4 gc = *(const f32x4*)(gamma + 32 + quad * 8);
    f32x4 gd = *(const f32x4*)(gamma + 32 + quad * 8 + 4);
    f32x4 ba = *(const f32x4*)(beta + quad * 8);
    f32x4 bb = *(const f32x4*)(beta + quad * 8 + 4);
    f32x4 bc = *(const f32x4*)(beta + 32 + quad * 8);
    f32x4 bd = *(const f32x4*)(beta + 32 + quad * 8 + 4);
    bf16x8 a0, a1;
    #pragma unroll
    for (int j = 0; j < 4; ++j) {
        a0[j]     = (short)f2bf(fmaf((xa[j] - mu) * rinv, ga[j], ba[j]));
        a0[4 + j] = (short)f2bf(fmaf((xb[j] - mu) * rinv, gb[j], bb[j]));
        a1[j]     = (short)f2bf(fmaf((xc[j] - mu) * rinv, gc[j], bc[j]));
        a1[4 + j] = (short)f2bf(fmaf((xd[j] - mu) * rinv, gd[j], bd[j]));
    }
    *(bf16x8*)(xnb + (long)rowA * D + quad * 8) = a0;
    *(bf16x8*)(xnb + (long)rowA * D + 32 + quad * 8) = a1;

    float bqc[4], bksc[4], bkdc[4];
    #pragma unroll
    for (int t = 0; t < 4; ++t) {
        bqc[t] = bq[t * 16 + c]; bksc[t] = bks[t * 16 + c]; bkdc[t] = bkd[t * 16 + c];
    }

    // GEMM1: q
    f32x4 accq[4];
    #pragma unroll
    for (int t = 0; t < 4; ++t) {
        bf16x8 b0 = *(const bf16x8*)(WqB + ((t * 2 + 0) * 64 + lane) * 8);
        bf16x8 b1 = *(const bf16x8*)(WqB + ((t * 2 + 1) * 64 + lane) * 8);
        f32x4 z = {0.f, 0.f, 0.f, 0.f};
        z = __builtin_amdgcn_mfma_f32_16x16x32_bf16(a0, b0, z, 0, 0, 0);
        z = __builtin_amdgcn_mfma_f32_16x16x32_bf16(a1, b1, z, 0, 0, 0);
        accq[t] = z;
    }
    #pragma unroll
    for (int r = 0; r < 4; ++r) {
        float qv[4], ss = 0.f, sd = 0.f;
        #pragma unroll
        for (int t = 0; t < 4; ++t) {
            qv[t] = accq[t][r] + bqc[t];
            ss = fmaf(qv[t], bksc[t], ss);
            sd = fmaf(qv[t], bkdc[t], sd);
        }
        #pragma unroll
        for (int o = 1; o < 16; o <<= 1) { ss += __shfl_xor(ss, o); sd += __shfl_xor(sd, o); }
        int nrow = n0 + quad * 4 + r;
        if (active && c == 0 && nrow < N) { bqs[nrow] = ss; bqd[nrow] = sd; }
        #pragma unroll
        for (int t = 0; t < 4; ++t)
            qtile[w][(quad * 4 + r) * 64 + t * 16 + c] = f2bf(qv[t]);
    }
    __syncthreads();

    // GEMM2: qks / qkd -> stored pi-permuted (pos c*4+t holds dim t*16+c)
    const u16* qrow = &qtile[w][c * 64 + quad * 8];
    bf16x8 q0 = *(const bf16x8*)(qrow);
    bf16x8 q1 = *(const bf16x8*)(qrow + 32);
    #pragma unroll
    for (int t = 0; t < 4; ++t) {
        bf16x8 bs0 = *(const bf16x8*)(WksB + ((t * 2 + 0) * 64 + lane) * 8);
        bf16x8 bs1 = *(const bf16x8*)(WksB + ((t * 2 + 1) * 64 + lane) * 8);
        bf16x8 bd0 = *(const bf16x8*)(WkdB + ((t * 2 + 0) * 64 + lane) * 8);
        bf16x8 bd1 = *(const bf16x8*)(WkdB + ((t * 2 + 1) * 64 + lane) * 8);
        f32x4 zs = {0.f, 0.f, 0.f, 0.f}, zd = {0.f, 0.f, 0.f, 0.f};
        zs = __builtin_amdgcn_mfma_f32_16x16x32_bf16(q0, bs0, zs, 0, 0, 0);
        zs = __builtin_amdgcn_mfma_f32_16x16x32_bf16(q1, bs1, zs, 0, 0, 0);
        zd = __builtin_amdgcn_mfma_f32_16x16x32_bf16(q0, bd0, zd, 0, 0, 0);
        zd = __builtin_amdgcn_mfma_f32_16x16x32_bf16(q1, bd1, zd, 0, 0, 0);
        #pragma unroll
        for (int r = 0; r < 4; ++r) {
            stile[w][0][(quad * 4 + r) * 64 + c * 4 + t] = f2bf(zs[r]);
            stile[w][1][(quad * 4 + r) * 64 + c * 4 + t] = f2bf(zd[r]);
        }
    }
    __builtin_amdgcn_s_barrier();  // wave-local LDS is consistent; barrier for safety of qtile reuse
    if (active) {
        if (n0 + 16 <= N) {
            const u16x8* s0p = (const u16x8*)&stile[w][0][0];
            const u16x8* s1p = (const u16x8*)&stile[w][1][0];
            u16x8* d0p = (u16x8*)(qksb + (long)n0 * D);
            u16x8* d1p = (u16x8*)(qkdb + (long)n0 * D);
            d0p[2 * lane] = s0p[2 * lane];
            d0p[2 * lane + 1] = s0p[2 * lane + 1];
            d1p[2 * lane] = s1p[2 * lane];
            d1p[2 * lane + 1] = s1p[2 * lane + 1];
        } else {
            for (int i = lane; i < (N - n0) * D; i += 64) {
                qksb[(long)n0 * D + i] = stile[w][0][i];
                qkdb[(long)n0 * D + i] = stile[w][1][i];
            }
        }
    }
}

// ---- edge pass: MFMA 16 edges/tile, prefetched streams, permuted q gather
//      (1x 8B load/lane) and permuted pk-f16 atomics (2 adjacent/lane, no shuffles)
__global__ __launch_bounds__(256) void edge_pass(
    const int* __restrict__ ei, const float* __restrict__ et, const float* __restrict__ esame,
    const u16* __restrict__ xnb, const u16* __restrict__ WtB,
    const float* __restrict__ Wt, const float* __restrict__ bt,
    const u16* __restrict__ qksb, const u16* __restrict__ qkdb,
    const float* __restrict__ bqs, const float* __restrict__ bqd,
    u16* __restrict__ As, u16* __restrict__ Ad,
    float* __restrict__ den_s, float* __restrict__ den_d, int E)
{
    const int lane = threadIdx.x & 63;
    const int c = lane & 15, quad = lane >> 4;
    const int wave = blockIdx.x * 4 + (threadIdx.x >> 6);
    const int nwaves = gridDim.x * 4;

    bf16x8 bfrag[8];
    #pragma unroll
    for (int f = 0; f < 8; ++f)
        bfrag[f] = *(const bf16x8*)(WtB + (f * 64 + lane) * 8);

    float btc[4], w64c[4], dva[4];
    #pragma unroll
    for (int t = 0; t < 4; ++t) {
        int dim = t * 16 + c;
        btc[t] = bt[dim];
        w64c[t] = Wt[dim * 65 + 64];
        dva[t] = 200.0f * expf(-9.210340371976184f * (float)(2 * (dim >> 1)) * (1.0f / 64.0f));
    }
    const float phoff = (c & 1) ? 1.5707963267948966f : 0.0f;  // cos = sin(x+pi/2)

    const long estride = (long)nwaves * 16;
    long e0 = (long)wave * 16;
    if (e0 >= E) return;

    // prologue loads
    int srcL, dstL; float tL, sameL;
    {
        int e = (int)e0 + c; int ec = e < E ? e : E - 1;
        srcL = ei[ec]; dstL = ei[E + ec]; tL = et[ec]; sameL = esame[ec];
    }
    const u16* ar = xnb + (long)srcL * D + quad * 8;
    bf16x8 a0 = *(const bf16x8*)(ar);
    bf16x8 a1 = *(const bf16x8*)(ar + 32);

    while (true) {
        // MFMA for current tile
        f32x4 acc[4];
        #pragma unroll
        for (int t = 0; t < 4; ++t) {
            f32x4 z = {0.f, 0.f, 0.f, 0.f};
            z = __builtin_amdgcn_mfma_f32_16x16x32_bf16(a0, bfrag[t * 2 + 0], z, 0, 0, 0);
            z = __builtin_amdgcn_mfma_f32_16x16x32_bf16(a1, bfrag[t * 2 + 1], z, 0, 0, 0);
            acc[t] = z;
        }

        // prefetch next tile (overlaps epilogue latency)
        long e1 = e0 + estride;
        bool more = e1 < E;
        int srcN, dstN; float tN, sameN;
        bf16x8 a0N, a1N;
        if (more) {
            int e = (int)e1 + c; int ec = e < E ? e : E - 1;
            srcN = ei[ec]; dstN = ei[E + ec]; tN = et[ec]; sameN = esame[ec];
            const u16* arN = xnb + (long)srcN * D + quad * 8;
            a0N = *(const bf16x8*)(arN);
            a1N = *(const bf16x8*)(arN + 32);
        }

        // epilogue
        #pragma unroll
        for (int r = 0; r < 4; ++r) {
            int m = quad * 4 + r;
            int dstm = __shfl(dstL, m);
            float tm = __shfl(tL, m);
            bool same = __shfl(sameL, m) > 0.5f;

            const u16* qrow = (same ? qksb : qkdb) + (long)dstm * D + c * 4;
            ushort4 q4 = *(const ushort4*)qrow;

            float xtv[4];
            #pragma unroll
            for (int t = 0; t < 4; ++t) {
                float v = gelu_tanh(acc[t][r] + fmaf(tm, w64c[t], btc[t]));
                v += __sinf(fmaf(tm, dva[t], phoff));
                xtv[t] = v;
            }
            float p = xtv[0] * bf2f(q4.x);
            p = fmaf(xtv[1], bf2f(q4.y), p);
            p = fmaf(xtv[2], bf2f(q4.z), p);
            p = fmaf(xtv[3], bf2f(q4.w), p);
            #pragma unroll
            for (int o = 1; o < 16; o <<= 1) p += __shfl_xor(p, o);
            bool valid = (e0 + m) < E;
            float ex = valid ? __expf((p + (same ? bqs[dstm] : bqd[dstm])) * 0.125f) : 0.0f;
            if (c == 0) atomicAdd(same ? &den_s[dstm] : &den_d[dstm], ex);

            u16* arow = (same ? As : Ad) + (long)dstm * D + c * 4;
            atomic_pk_add_f16(arow, ex * xtv[0], ex * xtv[1]);
            atomic_pk_add_f16(arow + 2, ex * xtv[2], ex * xtv[3]);
        }

        if (!more) break;
        e0 = e1; dstL = dstN; tL = tN; sameL = sameN; a0 = a0N; a1 = a1N;
    }
}

// ---- node post, MFMA: aggr = inv*(As@Wvs^T + Ad@Wvd^T) + (dens*inv)*bvs + (dend*inv)*bvd
//      out = x + gelu(aggr)    (As/Ad f16 pi-permuted; WvsB/WvdB k-permuted to match)
__global__ __launch_bounds__(256) void vgemm(
    const float* __restrict__ x, const u16* __restrict__ As, const u16* __restrict__ Ad,
    const float* __restrict__ den_s, const float* __restrict__ den_d,
    const u16* __restrict__ WvsB, const u16* __restrict__ WvdB,
    const float* __restrict__ bvs, const float* __restrict__ bvd,
    float* __restrict__ out, int N)
{
    const int lane = threadIdx.x & 63;
    const int c = lane & 15, quad = lane >> 4;
    const int wave = blockIdx.x * 4 + (threadIdx.x >> 6);
    const int n0r = wave * 16;
    if (n0r >= N) return;
    const int n0 = n0r;
    const int rowA = (n0 + c < N) ? n0 + c : N - 1;

    float bvsc[4], bvdc[4];
    #pragma unroll
    for (int t = 0; t < 4; ++t) { bvsc[t] = bvs[t * 16 + c]; bvdc[t] = bvd[t * 16 + c]; }

    const u16* srow = As + (long)rowA * D + quad * 8;
    const u16* drow = Ad + (long)rowA * D + quad * 8;
    f16x8 s0 = *(const f16x8*)(srow);
    f16x8 s1 = *(const f16x8*)(srow + 32);
    f16x8 d0 = *(const f16x8*)(drow);
    f16x8 d1 = *(const f16x8*)(drow + 32);

    f32x4 acc[4];
    #pragma unroll
    for (int t = 0; t < 4; ++t) {
        f16x8 bs0 = *(const f16x8*)(WvsB + ((t * 2 + 0) * 64 + lane) * 8);
        f16x8 bs1 = *(const f16x8*)(WvsB + ((t * 2 + 1) * 64 + lane) * 8);
        f16x8 bd0 = *(const f16x8*)(WvdB + ((t * 2 + 0) * 64 + lane) * 8);
        f16x8 bd1 = *(const f16x8*)(WvdB + ((t * 2 + 1) * 64 + lane) * 8);
        f32x4 z = {0.f, 0.f, 0.f, 0.f};
        z = __builtin_amdgcn_mfma_f32_16x16x32_f16(s0, bs0, z, 0, 0, 0);
        z = __builtin_amdgcn_mfma_f32_16x16x32_f16(s1, bs1, z, 0, 0, 0);
        z = __builtin_amdgcn_mfma_f32_16x16x32_f16(d0, bd0, z, 0, 0, 0);
        z = __builtin_amdgcn_mfma_f32_16x16x32_f16(d1, bd1, z, 0, 0, 0);
        acc[t] = z;
    }

    #pragma unroll
    for (int r = 0; r < 4; ++r) {
        int n = n0 + quad * 4 + r;
        if (n >= N) continue;
        float ds = den_s[n], dd = den_d[n];
        float inv = 1.0f / (ds + dd + 1e-16f);
        float fs = ds * inv, fd = dd * inv;
        #pragma unroll
        for (int t = 0; t < 4; ++t) {
            long idx = (long)n * D + t * 16 + c;
            float o = fmaf(acc[t][r], inv, fmaf(fs, bvsc[t], fd * bvdc[t]));
            out[idx] = x[idx] + gelu_erf(o);
        }
    }
}

extern "C" void kernel_launch(void* const* d_in, const int* in_sizes, int n_in,
                              void* d_out, int out_size, void* d_ws, size_t ws_size,
                              hipStream_t stream) {
    const float* x        = (const float*)d_in[0];
    const int*   ei       = (const int*)d_in[1];
    const float* et       = (const float*)d_in[2];
    const float* esame    = (const float*)d_in[4];
    const float* ln_gamma = (const float*)d_in[5];
    const float* ln_beta  = (const float*)d_in[6];
    const float* Wt  = (const float*)d_in[7];
    const float* bt  = (const float*)d_in[8];
    const float* Wq  = (const float*)d_in[9];
    const float* bq  = (const float*)d_in[10];
    const float* Wks = (const float*)d_in[11];
    const float* bks = (const float*)d_in[12];
    const float* Wkd = (const float*)d_in[13];
    const float* bkd = (const float*)d_in[14];
    const float* Wvs = (const float*)d_in[15];
    const float* bvs = (const float*)d_in[16];
    const float* Wvd = (const float*)d_in[17];
    const float* bvd = (const float*)d_in[18];
    float* out = (float*)d_out;

    const int N = in_sizes[0] / D;   // 50000
    const int E = in_sizes[2];       // 800000

    u16* As = (u16*)d_ws;                 // N*64 f16 (pi-permuted)
    u16* Ad = As + (long)N * D;
    float* dens = (float*)(Ad + (long)N * D);
    float* dend = dens + N;
    float* bqs = dend + N;
    float* bqd = bqs + N;
    u16* xnb  = (u16*)(bqd + N);          // N*64 bf16
    u16* qksb = xnb + (long)N * D;        // N*64 bf16 (pi-permuted)
    u16* qkdb = qksb + (long)N * D;
    u16* WtB  = qkdb + (long)N * D;       // 4096 each
    u16* WqB  = WtB + 4096;
    u16* WksB = WqB + 4096;
    u16* WkdB = WksB + 4096;
    u16* WvsB = WkdB + 4096;
    u16* WvdB = WvsB + 4096;

    prep_weights<<<48, 64, 0, stream>>>(Wt, Wq, Wks, Wkd, Wvs, Wvd,
                                        WtB, WqB, WksB, WkdB, WvsB, WvdB);
    const int nblk16 = ((N + 15) / 16 + 3) / 4;
    qgemm<<<nblk16, 256, 0, stream>>>(x, ln_gamma, ln_beta, WqB, WksB, WkdB,
                                      bq, bks, bkd, xnb, qksb, qkdb, bqs, bqd,
                                      As, Ad, dens, dend, N);
    edge_pass<<<2048, 256, 0, stream>>>(ei, et, esame, xnb, WtB, Wt, bt,
                                        qksb, qkdb, bqs, bqd, As, Ad, dens, dend, E);
    vgemm<<<nblk16, 256, 0, stream>>>(x, As, Ad, dens, dend, WvsB, WvdB, bvs, bvd, out, N);
}